// Round 8
// baseline (153.651 us; speedup 1.0000x reference)
//
#include <hip/hip_runtime.h>
#include <math.h>

#define NPTS 4096
#define KNN  20
#define NOUT 64
#define QPB  8               // queries (= waves) per block
#define BLKT (QPB * 64)      // 512 threads
#define PCAP 128             // per-wave survivor pool capacity
#define HALF 2048            // candidates staged in LDS (phase A)

// monotone float->uint map (total order preserved)
__device__ __forceinline__ unsigned ord32(float f) {
    unsigned u = __float_as_uint(f);
    int m = ((int)u) >> 31;
    return u ^ ((unsigned)m | 0x80000000u);
}

__device__ __forceinline__ int mbcnt64(unsigned long long m) {
    return __builtin_amdgcn_mbcnt_hi((unsigned)(m >> 32),
           __builtin_amdgcn_mbcnt_lo((unsigned)m, 0));
}

// prologue: xq[b][j] = (x0, x1, x2, -(x0^2+x1^2+x2^2))
__global__ __launch_bounds__(256) void pack_kernel(const float* __restrict__ x,
                                                   float4* __restrict__ xq) {
    const int i = blockIdx.x * 256 + threadIdx.x;   // over B*NPTS
    const int b = i >> 12, j = i & (NPTS - 1);
    const float* xb = x + (size_t)b * 3 * NPTS;
    const float a0 = xb[j], a1 = xb[NPTS + j], a2 = xb[2 * NPTS + j];
    xq[i] = make_float4(a0, a1, a2, -fmaf(a0, a0, fmaf(a1, a1, a2 * a2)));
}

__global__ __launch_bounds__(BLKT, 6) void edgeconv_kernel(
    const float4* __restrict__ xq,    // (B, N) packed points
    const float* __restrict__ Wm,     // (64, 6)
    const float* __restrict__ gamma,
    const float* __restrict__ beta,
    const float* __restrict__ mean,
    const float* __restrict__ var,
    float* __restrict__ out)          // (B, 64, N)
{
    const int bid = blockIdx.x;
    const int b   = bid >> 9;                    // 512 blocks per batch
    const int n0  = (bid & 511) * QPB;
    const int t    = threadIdx.x;
    const int lane = t & 63;
    const int w    = t >> 6;

    __shared__ float4 tile[HALF];                       // 32 KB, candidates 0..2047
    __shared__ unsigned long long pool[QPB * PCAP];     // 8 KB
    __shared__ unsigned idxs[QPB][KNN];                 // winner buffer (no aliasing)
    __shared__ float outT[NOUT * 9];                    // padded transpose buffer
    __shared__ int cnt[QPB];                            // per-wave pool counters

    const float4* xqb = xq + (size_t)b * NPTS;

    if (lane == 0) cnt[w] = 0;                          // own wave's counter only

    // ---- stage phase-A points into LDS ----
    #pragma unroll
    for (int k2 = 0; k2 < HALF / BLKT; ++k2) {          // 4 iters
        const int c = t + k2 * BLKT;
        tile[c] = xqb[c];
    }
    __syncthreads();

    // ---- this wave's query point (uniform -> scalar load) ----
    const int nu = __builtin_amdgcn_readfirstlane(n0 + w);
    const float4 pv = xqb[nu];
    const float q0 = 2.f * pv.x, q1 = 2.f * pv.y, q2 = 2.f * pv.z;

    // ---- phase A: 2048 LDS candidates, keep d[32] in regs ----
    float d[32];
    float vmax = -INFINITY;
    #pragma unroll
    for (int g = 0; g < 4; ++g) {
        float4 cc[8];
        #pragma unroll
        for (int u = 0; u < 8; ++u) cc[u] = tile[(g * 8 + u) * 64 + lane];
        #pragma unroll
        for (int u = 0; u < 8; ++u) {
            const float e = fmaf(q0, cc[u].x, fmaf(q1, cc[u].y, fmaf(q2, cc[u].z, cc[u].w)));
            d[g * 8 + u] = e;
            vmax = fmaxf(vmax, e);
        }
    }

    // ---- threshold: bitonic (desc) of 64 phase-A lane maxima; T = 20th ----
    // The 20 top lane-maxima are 20 distinct candidates >= T, so the global
    // 20th-best >= T; hence {all 4096 candidates >= T} contains the true top-20.
    float T;
    {
        float v = vmax;
        #pragma unroll
        for (int k = 2; k <= 64; k <<= 1) {
            #pragma unroll
            for (int j = k >> 1; j > 0; j >>= 1) {
                const float o = __shfl_xor(v, j, 64);
                const bool keep_min = ((lane & j) == 0) == ((lane & k) != 0);
                v = keep_min ? fminf(v, o) : fmaxf(v, o);
            }
        }
        T = __shfl(v, 19, 64);
    }

    // ---- phase-A survivors: exec-masked atomic append (scalar-pipe branch) ----
    const int invl = (NPTS - 1) - lane;
    #pragma unroll
    for (int j = 0; j < 32; ++j) {
        if (d[j] >= T) {
            const int pos = atomicAdd(&cnt[w], 1);
            if (pos < PCAP)
                pool[w * PCAP + pos] =
                    ((unsigned long long)ord32(d[j]) << 32) |
                    (unsigned)(invl - j * 64);           // tie -> lower idx wins
        }
    }

    // ---- phase B: stream 2048 global candidates, filter vs T, no storage ----
    #pragma unroll
    for (int g = 4; g < 8; ++g) {
        float4 cc[8];
        #pragma unroll
        for (int u = 0; u < 8; ++u) cc[u] = xqb[(g * 8 + u) * 64 + lane];
        #pragma unroll
        for (int u = 0; u < 8; ++u) {
            const float e = fmaf(q0, cc[u].x, fmaf(q1, cc[u].y, fmaf(q2, cc[u].z, cc[u].w)));
            if (e >= T) {
                const int pos = atomicAdd(&cnt[w], 1);
                if (pos < PCAP)
                    pool[w * PCAP + pos] =
                        ((unsigned long long)ord32(e) << 32) |
                        (unsigned)(invl - (g * 8 + u) * 64);
            }
        }
    }

    const int cntw = __builtin_amdgcn_readfirstlane(cnt[w]);
    const int cnt_ = (cntw < PCAP) ? cntw : PCAP;        // cnt >= 20 guaranteed

    // ---- exact top-20 set selection (order irrelevant for max-pool) ----
    unsigned long long kk = 0ull;
    if (lane < cnt_) kk = pool[w * PCAP + lane];

    if (cnt_ <= 64) {
        const unsigned key = (unsigned)(kk >> 32);
        unsigned v = key;
        #pragma unroll
        for (int k = 2; k <= 64; k <<= 1) {
            #pragma unroll
            for (int j = k >> 1; j > 0; j >>= 1) {
                const unsigned o = (unsigned)__shfl_xor((int)v, j, 64);
                const bool keep_min = ((lane & j) == 0) == ((lane & k) != 0);
                v = keep_min ? min(v, o) : max(v, o);
            }
        }
        const unsigned K20 = (unsigned)__shfl((int)v, 19, 64);
        const unsigned long long ge = __ballot(key >= K20);  // pad key never matches
        if (__popcll(ge) == KNN) {
            if (key >= K20) idxs[w][mbcnt64(ge)] = (unsigned)kk;
        } else {
            // rare tie path: full u64 sort (value desc, index asc)
            unsigned long long key64 = kk;
            #pragma unroll
            for (int k = 2; k <= 64; k <<= 1) {
                #pragma unroll
                for (int j = k >> 1; j > 0; j >>= 1) {
                    const unsigned long long o = __shfl_xor(key64, j, 64);
                    const bool keep_min = ((lane & j) == 0) == ((lane & k) != 0);
                    const unsigned long long mn = (key64 < o) ? key64 : o;
                    const unsigned long long mx = (key64 < o) ? o : key64;
                    key64 = keep_min ? mn : mx;
                }
            }
            if (lane < KNN) idxs[w][lane] = (unsigned)key64;
        }
    } else {
        // overflow path (~10%): 20 extraction rounds; winners to idxs (disjoint).
        for (int r = 0; r < KNN; ++r) {
            unsigned long long bk = 0ull; int bp = -1;
            for (int i = lane; i < cnt_; i += 64) {
                const unsigned long long e = pool[w * PCAP + i];
                if (e > bk) { bk = e; bp = i; }
            }
            unsigned long long rb = bk;
            #pragma unroll
            for (int s = 32; s > 0; s >>= 1) {
                const unsigned long long o = __shfl_xor(rb, s, 64);
                if (o > rb) rb = o;
            }
            if (bk == rb && bp >= 0) pool[w * PCAP + bp] = 0ull;  // unique keys
            if (lane == 0) idxs[w][r] = (unsigned)rb;
        }
    }

    // pull the 20 inverted indices into a register
    const unsigned myidx = idxs[w][(lane < KNN) ? lane : 0];

    // ---- epilogue: lane = output channel; neighbors via scalar loads ----
    const int o = lane;
    const float iv   = gamma[o] / sqrtf(var[o] + 1e-5f);
    const float bias = beta[o] - mean[o] * iv;
    const float* Wr = Wm + o * 6;
    const float w0p = Wr[0] * iv, w1p = Wr[1] * iv, w2p = Wr[2] * iv;
    const float w3p = Wr[3] * iv, w4p = Wr[4] * iv, w5p = Wr[5] * iv;
    const float basep = fmaf(w3p, pv.x, fmaf(w4p, pv.y, fmaf(w5p, pv.z, bias)));

    float best = -INFINITY;
    #pragma unroll
    for (int k = 0; k < KNN; ++k) {
        const int lk = __builtin_amdgcn_readlane((int)myidx, k);
        const int gi = __builtin_amdgcn_readfirstlane((NPTS - 1) - lk);
        const float4 f = xqb[gi];                        // uniform -> s_load_dwordx4
        float y = fmaf(w0p, f.x - pv.x,
                   fmaf(w1p, f.y - pv.y,
                    fmaf(w2p, f.z - pv.z, basep)));
        y = fmaxf(y, 0.2f * y);                          // LeakyReLU
        best = fmaxf(best, y);
    }

    outT[o * 9 + w] = best;
    __syncthreads();

    // ---- output: 2 x float4 per channel row ----
    if (t < NOUT * 2) {
        const int oo = t >> 1, seg = t & 1;
        const int sb = oo * 9 + seg * 4;
        float4 vv;
        vv.x = outT[sb + 0]; vv.y = outT[sb + 1];
        vv.z = outT[sb + 2]; vv.w = outT[sb + 3];
        *(float4*)(out + ((size_t)b * NOUT + oo) * NPTS + n0 + seg * 4) = vv;
    }
}

extern "C" void kernel_launch(void* const* d_in, const int* in_sizes, int n_in,
                              void* d_out, int out_size, void* d_ws, size_t ws_size,
                              hipStream_t stream) {
    const float* x     = (const float*)d_in[0];
    const float* Wm    = (const float*)d_in[1];
    const float* gamma = (const float*)d_in[2];
    const float* beta  = (const float*)d_in[3];
    const float* mean  = (const float*)d_in[4];
    const float* var   = (const float*)d_in[5];
    float* out = (float*)d_out;
    float4* xq = (float4*)d_ws;                    // B*NPTS float4 = 512 KB

    const int B = in_sizes[0] / (3 * NPTS);        // 8
    pack_kernel<<<B * NPTS / 256, 256, 0, stream>>>(x, xq);
    const int nblocks = B * (NPTS / QPB);          // 8 * 512 = 4096
    edgeconv_kernel<<<nblocks, BLKT, 0, stream>>>(xq, Wm, gamma, beta, mean, var, out);
}

// Round 9
// 150.820 us; speedup vs baseline: 1.0188x; 1.0188x over previous
//
#include <hip/hip_runtime.h>
#include <math.h>

#define NPTS 4096
#define KNN  20
#define NOUT 64
#define QPB  8               // queries (= waves) per block
#define BLKT (QPB * 64)      // 512 threads
#define PCAP 128             // per-wave survivor pool capacity
#define HALF 2048            // candidates staged in LDS (phase A)

// monotone float->uint map (total order preserved)
__device__ __forceinline__ unsigned ord32(float f) {
    unsigned u = __float_as_uint(f);
    int m = ((int)u) >> 31;
    return u ^ ((unsigned)m | 0x80000000u);
}

__device__ __forceinline__ int mbcnt64(unsigned long long m) {
    return __builtin_amdgcn_mbcnt_hi((unsigned)(m >> 32),
           __builtin_amdgcn_mbcnt_lo((unsigned)m, 0));
}

// prologue: xq[b][j] = (x0, x1, x2, -(x0^2+x1^2+x2^2))
__global__ __launch_bounds__(256) void pack_kernel(const float* __restrict__ x,
                                                   float4* __restrict__ xq) {
    const int i = blockIdx.x * 256 + threadIdx.x;   // over B*NPTS
    const int b = i >> 12, j = i & (NPTS - 1);
    const float* xb = x + (size_t)b * 3 * NPTS;
    const float a0 = xb[j], a1 = xb[NPTS + j], a2 = xb[2 * NPTS + j];
    xq[i] = make_float4(a0, a1, a2, -fmaf(a0, a0, fmaf(a1, a1, a2 * a2)));
}

__global__ __launch_bounds__(BLKT, 6) void edgeconv_kernel(
    const float4* __restrict__ xq,    // (B, N) packed points
    const float* __restrict__ Wm,     // (64, 6)
    const float* __restrict__ gamma,
    const float* __restrict__ beta,
    const float* __restrict__ mean,
    const float* __restrict__ var,
    float* __restrict__ out)          // (B, 64, N)
{
    const int bid = blockIdx.x;
    const int b   = bid >> 9;                    // 512 blocks per batch
    const int n0  = (bid & 511) * QPB;
    const int t    = threadIdx.x;
    const int lane = t & 63;
    const int w    = t >> 6;

    __shared__ float4 tile[HALF];                       // 32 KB, candidates 0..2047
    __shared__ unsigned long long pool[QPB * PCAP];     // 8 KB
    __shared__ unsigned idxs[QPB][KNN];                 // winner buffer (no aliasing)
    __shared__ float outT[NOUT * 9];                    // padded transpose buffer
    __shared__ int cnt[QPB];                            // per-wave pool counters

    const float4* xqb = xq + (size_t)b * NPTS;

    if (lane == 0) cnt[w] = 0;                          // own wave's counter only

    // ---- stage phase-A points into LDS ----
    #pragma unroll
    for (int k2 = 0; k2 < HALF / BLKT; ++k2) {          // 4 iters
        const int c = t + k2 * BLKT;
        tile[c] = xqb[c];
    }
    __syncthreads();

    // ---- this wave's query point (uniform -> scalar load) ----
    const int nu = __builtin_amdgcn_readfirstlane(n0 + w);
    const float4 pv = xqb[nu];
    const float q0 = 2.f * pv.x, q1 = 2.f * pv.y, q2 = 2.f * pv.z;

    // ---- pass A1: vmax over 2048 LDS candidates (no storage) ----
    float vmax = -INFINITY;
    #pragma unroll
    for (int g = 0; g < 4; ++g) {
        float4 cc[8];
        #pragma unroll
        for (int u = 0; u < 8; ++u) cc[u] = tile[(g * 8 + u) * 64 + lane];
        #pragma unroll
        for (int u = 0; u < 8; ++u) {
            const float e = fmaf(q0, cc[u].x, fmaf(q1, cc[u].y, fmaf(q2, cc[u].z, cc[u].w)));
            vmax = fmaxf(vmax, e);
        }
    }

    // ---- threshold: bitonic (desc) of 64 phase-A lane maxima; T = 20th ----
    // The 20 top lane-maxima are 20 distinct candidates >= T, so the global
    // 20th-best >= T; hence {all 4096 candidates >= T} contains the true top-20.
    float T;
    {
        float v = vmax;
        #pragma unroll
        for (int k = 2; k <= 64; k <<= 1) {
            #pragma unroll
            for (int j = k >> 1; j > 0; j >>= 1) {
                const float o = __shfl_xor(v, j, 64);
                const bool keep_min = ((lane & j) == 0) == ((lane & k) != 0);
                v = keep_min ? fminf(v, o) : fmaxf(v, o);
            }
        }
        T = __shfl(v, 19, 64);
    }

    // ---- pass A2: re-read tile, recompute e (bit-identical), append >= T ----
    const int invl = (NPTS - 1) - lane;
    #pragma unroll
    for (int g = 0; g < 4; ++g) {
        float4 cc[8];
        #pragma unroll
        for (int u = 0; u < 8; ++u) cc[u] = tile[(g * 8 + u) * 64 + lane];
        #pragma unroll
        for (int u = 0; u < 8; ++u) {
            const float e = fmaf(q0, cc[u].x, fmaf(q1, cc[u].y, fmaf(q2, cc[u].z, cc[u].w)));
            if (e >= T) {
                const int pos = atomicAdd(&cnt[w], 1);
                if (pos < PCAP)
                    pool[w * PCAP + pos] =
                        ((unsigned long long)ord32(e) << 32) |
                        (unsigned)(invl - (g * 8 + u) * 64);   // tie -> lower idx
            }
        }
    }

    // ---- phase B: stream 2048 global candidates, fused filter ----
    #pragma unroll
    for (int g = 4; g < 8; ++g) {
        float4 cc[8];
        #pragma unroll
        for (int u = 0; u < 8; ++u) cc[u] = xqb[(g * 8 + u) * 64 + lane];
        #pragma unroll
        for (int u = 0; u < 8; ++u) {
            const float e = fmaf(q0, cc[u].x, fmaf(q1, cc[u].y, fmaf(q2, cc[u].z, cc[u].w)));
            if (e >= T) {
                const int pos = atomicAdd(&cnt[w], 1);
                if (pos < PCAP)
                    pool[w * PCAP + pos] =
                        ((unsigned long long)ord32(e) << 32) |
                        (unsigned)(invl - (g * 8 + u) * 64);
            }
        }
    }

    const int cntw = __builtin_amdgcn_readfirstlane(cnt[w]);
    const int cnt_ = (cntw < PCAP) ? cntw : PCAP;        // cnt >= 20 guaranteed

    // ---- exact top-20 set selection (order irrelevant for max-pool) ----
    unsigned long long kk = 0ull;
    if (lane < cnt_) kk = pool[w * PCAP + lane];

    if (cnt_ <= 64) {
        const unsigned key = (unsigned)(kk >> 32);
        unsigned v = key;
        #pragma unroll
        for (int k = 2; k <= 64; k <<= 1) {
            #pragma unroll
            for (int j = k >> 1; j > 0; j >>= 1) {
                const unsigned o = (unsigned)__shfl_xor((int)v, j, 64);
                const bool keep_min = ((lane & j) == 0) == ((lane & k) != 0);
                v = keep_min ? min(v, o) : max(v, o);
            }
        }
        const unsigned K20 = (unsigned)__shfl((int)v, 19, 64);
        const unsigned long long ge = __ballot(key >= K20);  // pad key never matches
        if (__popcll(ge) == KNN) {
            if (key >= K20) idxs[w][mbcnt64(ge)] = (unsigned)kk;
        } else {
            // rare tie path: full u64 sort (value desc, index asc)
            unsigned long long key64 = kk;
            #pragma unroll
            for (int k = 2; k <= 64; k <<= 1) {
                #pragma unroll
                for (int j = k >> 1; j > 0; j >>= 1) {
                    const unsigned long long o = __shfl_xor(key64, j, 64);
                    const bool keep_min = ((lane & j) == 0) == ((lane & k) != 0);
                    const unsigned long long mn = (key64 < o) ? key64 : o;
                    const unsigned long long mx = (key64 < o) ? o : key64;
                    key64 = keep_min ? mn : mx;
                }
            }
            if (lane < KNN) idxs[w][lane] = (unsigned)key64;
        }
    } else {
        // overflow path (rare): 20 extraction rounds; winners to idxs (disjoint).
        for (int r = 0; r < KNN; ++r) {
            unsigned long long bk = 0ull; int bp = -1;
            for (int i = lane; i < cnt_; i += 64) {
                const unsigned long long e = pool[w * PCAP + i];
                if (e > bk) { bk = e; bp = i; }
            }
            unsigned long long rb = bk;
            #pragma unroll
            for (int s = 32; s > 0; s >>= 1) {
                const unsigned long long o = __shfl_xor(rb, s, 64);
                if (o > rb) rb = o;
            }
            if (bk == rb && bp >= 0) pool[w * PCAP + bp] = 0ull;  // unique keys
            if (lane == 0) idxs[w][r] = (unsigned)rb;
        }
    }

    // pull the 20 inverted indices into a register
    const unsigned myidx = idxs[w][(lane < KNN) ? lane : 0];

    // ---- epilogue: lane = output channel; neighbors via scalar loads ----
    const int o = lane;
    const float iv   = gamma[o] / sqrtf(var[o] + 1e-5f);
    const float bias = beta[o] - mean[o] * iv;
    const float* Wr = Wm + o * 6;
    const float w0p = Wr[0] * iv, w1p = Wr[1] * iv, w2p = Wr[2] * iv;
    const float w3p = Wr[3] * iv, w4p = Wr[4] * iv, w5p = Wr[5] * iv;
    // y = w0p*(f0-p0)+w1p*(f1-p1)+w2p*(f2-p2) + w3p*p0+w4p*p1+w5p*p2 + bias
    //   = w0p*f0 + w1p*f1 + w2p*f2 + base2
    const float basep = fmaf(w3p, pv.x, fmaf(w4p, pv.y, fmaf(w5p, pv.z, bias)));
    const float base2 = basep - fmaf(w0p, pv.x, fmaf(w1p, pv.y, w2p * pv.z));

    float best = -INFINITY;
    #pragma unroll
    for (int k = 0; k < KNN; ++k) {
        const int lk = __builtin_amdgcn_readlane((int)myidx, k);
        const int gi = __builtin_amdgcn_readfirstlane((NPTS - 1) - lk);
        const float4 f = xqb[gi];                        // uniform -> s_load_dwordx4
        float y = fmaf(w0p, f.x, fmaf(w1p, f.y, fmaf(w2p, f.z, base2)));
        y = fmaxf(y, 0.2f * y);                          // LeakyReLU
        best = fmaxf(best, y);
    }

    outT[o * 9 + w] = best;
    __syncthreads();

    // ---- output: 2 x float4 per channel row ----
    if (t < NOUT * 2) {
        const int oo = t >> 1, seg = t & 1;
        const int sb = oo * 9 + seg * 4;
        float4 vv;
        vv.x = outT[sb + 0]; vv.y = outT[sb + 1];
        vv.z = outT[sb + 2]; vv.w = outT[sb + 3];
        *(float4*)(out + ((size_t)b * NOUT + oo) * NPTS + n0 + seg * 4) = vv;
    }
}

extern "C" void kernel_launch(void* const* d_in, const int* in_sizes, int n_in,
                              void* d_out, int out_size, void* d_ws, size_t ws_size,
                              hipStream_t stream) {
    const float* x     = (const float*)d_in[0];
    const float* Wm    = (const float*)d_in[1];
    const float* gamma = (const float*)d_in[2];
    const float* beta  = (const float*)d_in[3];
    const float* mean  = (const float*)d_in[4];
    const float* var   = (const float*)d_in[5];
    float* out = (float*)d_out;
    float4* xq = (float4*)d_ws;                    // B*NPTS float4 = 512 KB

    const int B = in_sizes[0] / (3 * NPTS);        // 8
    pack_kernel<<<B * NPTS / 256, 256, 0, stream>>>(x, xq);
    const int nblocks = B * (NPTS / QPB);          // 8 * 512 = 4096
    edgeconv_kernel<<<nblocks, BLKT, 0, stream>>>(xq, Wm, gamma, beta, mean, var, out);
}

// Round 10
// 144.160 us; speedup vs baseline: 1.0658x; 1.0462x over previous
//
#include <hip/hip_runtime.h>
#include <math.h>

#define NPTS 4096
#define KNN  20
#define NOUT 64
#define WPB  8               // waves per block
#define QPW  2               // queries per wave
#define QBLK (WPB * QPW)     // 16 queries per block
#define BLKT (WPB * 64)      // 512 threads
#define PCAP 96              // per-query survivor pool capacity
#define HALF 2048            // candidates staged in LDS (phase A)

// monotone float->uint map (total order preserved)
__device__ __forceinline__ unsigned ord32(float f) {
    unsigned u = __float_as_uint(f);
    int m = ((int)u) >> 31;
    return u ^ ((unsigned)m | 0x80000000u);
}

__device__ __forceinline__ int mbcnt64(unsigned long long m) {
    return __builtin_amdgcn_mbcnt_hi((unsigned)(m >> 32),
           __builtin_amdgcn_mbcnt_lo((unsigned)m, 0));
}

// prologue: xq[b][j] = (x0, x1, x2, -(x0^2+x1^2+x2^2))
__global__ __launch_bounds__(256) void pack_kernel(const float* __restrict__ x,
                                                   float4* __restrict__ xq) {
    const int i = blockIdx.x * 256 + threadIdx.x;   // over B*NPTS
    const int b = i >> 12, j = i & (NPTS - 1);
    const float* xb = x + (size_t)b * 3 * NPTS;
    const float a0 = xb[j], a1 = xb[NPTS + j], a2 = xb[2 * NPTS + j];
    xq[i] = make_float4(a0, a1, a2, -fmaf(a0, a0, fmaf(a1, a1, a2 * a2)));
}

__global__ __launch_bounds__(BLKT, 6) void edgeconv_kernel(
    const float4* __restrict__ xq,    // (B, N) packed points
    const float* __restrict__ Wm,     // (64, 6)
    const float* __restrict__ gamma,
    const float* __restrict__ beta,
    const float* __restrict__ mean,
    const float* __restrict__ var,
    float* __restrict__ out)          // (B, 64, N)
{
    const int bid = blockIdx.x;
    const int b   = bid >> 8;                    // 256 blocks per batch
    const int n0  = (bid & 255) * QBLK;
    const int t    = threadIdx.x;
    const int lane = t & 63;
    const int w    = t >> 6;

    __shared__ float4 tile[HALF];                       // 32 KB
    __shared__ unsigned long long pool[QBLK * PCAP];    // 12 KB
    __shared__ unsigned idxs[QBLK][KNN];                // winner buffers
    __shared__ float outT[NOUT * (QBLK + 1)];           // padded transpose buf
    __shared__ int cnt[QBLK];                           // per-query pool counters

    const float4* xqb = xq + (size_t)b * NPTS;

    if (lane < QPW) cnt[QPW * w + lane] = 0;            // own wave's counters

    // ---- stage phase-A points into LDS ----
    #pragma unroll
    for (int k2 = 0; k2 < HALF / BLKT; ++k2) {          // 4 iters
        const int c = t + k2 * BLKT;
        tile[c] = xqb[c];
    }
    __syncthreads();

    // ---- this wave's two query points (uniform -> scalar loads) ----
    const int na = __builtin_amdgcn_readfirstlane(n0 + QPW * w);
    const int nb = na + 1;
    const float4 pva = xqb[na];
    const float4 pvb = xqb[nb];
    const float qa0 = 2.f * pva.x, qa1 = 2.f * pva.y, qa2 = 2.f * pva.z;
    const float qb0 = 2.f * pvb.x, qb1 = 2.f * pvb.y, qb2 = 2.f * pvb.z;

    // ---- pass A1: lane maxima over 2048 LDS candidates, both queries ----
    float vma = -INFINITY, vmb = -INFINITY;
    #pragma unroll
    for (int g = 0; g < 4; ++g) {
        float4 cc[8];
        #pragma unroll
        for (int u = 0; u < 8; ++u) cc[u] = tile[(g * 8 + u) * 64 + lane];
        #pragma unroll
        for (int u = 0; u < 8; ++u) {
            const float ea = fmaf(qa0, cc[u].x, fmaf(qa1, cc[u].y, fmaf(qa2, cc[u].z, cc[u].w)));
            const float eb = fmaf(qb0, cc[u].x, fmaf(qb1, cc[u].y, fmaf(qb2, cc[u].z, cc[u].w)));
            vma = fmaxf(vma, ea);
            vmb = fmaxf(vmb, eb);
        }
    }

    // ---- thresholds: two interleaved bitonic sorts (desc); T = 20th ----
    float Ta, Tb;
    {
        float va = vma, vb = vmb;
        #pragma unroll
        for (int k = 2; k <= 64; k <<= 1) {
            #pragma unroll
            for (int j = k >> 1; j > 0; j >>= 1) {
                const float oa = __shfl_xor(va, j, 64);
                const float ob = __shfl_xor(vb, j, 64);
                const bool keep_min = ((lane & j) == 0) == ((lane & k) != 0);
                va = keep_min ? fminf(va, oa) : fmaxf(va, oa);
                vb = keep_min ? fminf(vb, ob) : fmaxf(vb, ob);
            }
        }
        Ta = __shfl(va, 19, 64);
        Tb = __shfl(vb, 19, 64);
    }

    const int invl = (NPTS - 1) - lane;
    int* cnta = &cnt[QPW * w];
    int* cntb = &cnt[QPW * w + 1];
    unsigned long long* poola = pool + (QPW * w) * PCAP;
    unsigned long long* poolb = pool + (QPW * w + 1) * PCAP;

    // ---- pass A2: re-read tile, recompute (bit-identical), append >= T ----
    #pragma unroll
    for (int g = 0; g < 4; ++g) {
        float4 cc[8];
        #pragma unroll
        for (int u = 0; u < 8; ++u) cc[u] = tile[(g * 8 + u) * 64 + lane];
        #pragma unroll
        for (int u = 0; u < 8; ++u) {
            const float ea = fmaf(qa0, cc[u].x, fmaf(qa1, cc[u].y, fmaf(qa2, cc[u].z, cc[u].w)));
            const float eb = fmaf(qb0, cc[u].x, fmaf(qb1, cc[u].y, fmaf(qb2, cc[u].z, cc[u].w)));
            const unsigned tag = (unsigned)(invl - (g * 8 + u) * 64);
            if (ea >= Ta) {
                const int pos = atomicAdd(cnta, 1);
                if (pos < PCAP)
                    poola[pos] = ((unsigned long long)ord32(ea) << 32) | tag;
            }
            if (eb >= Tb) {
                const int pos = atomicAdd(cntb, 1);
                if (pos < PCAP)
                    poolb[pos] = ((unsigned long long)ord32(eb) << 32) | tag;
            }
        }
    }

    // ---- phase B: stream 2048 global candidates, fused dual filter ----
    #pragma unroll
    for (int g = 4; g < 8; ++g) {
        float4 cc[8];
        #pragma unroll
        for (int u = 0; u < 8; ++u) cc[u] = xqb[(g * 8 + u) * 64 + lane];
        #pragma unroll
        for (int u = 0; u < 8; ++u) {
            const float ea = fmaf(qa0, cc[u].x, fmaf(qa1, cc[u].y, fmaf(qa2, cc[u].z, cc[u].w)));
            const float eb = fmaf(qb0, cc[u].x, fmaf(qb1, cc[u].y, fmaf(qb2, cc[u].z, cc[u].w)));
            const unsigned tag = (unsigned)(invl - (g * 8 + u) * 64);
            if (ea >= Ta) {
                const int pos = atomicAdd(cnta, 1);
                if (pos < PCAP)
                    poola[pos] = ((unsigned long long)ord32(ea) << 32) | tag;
            }
            if (eb >= Tb) {
                const int pos = atomicAdd(cntb, 1);
                if (pos < PCAP)
                    poolb[pos] = ((unsigned long long)ord32(eb) << 32) | tag;
            }
        }
    }

    // ---- exact top-20 set selection, per query ----
    #pragma unroll
    for (int q = 0; q < QPW; ++q) {
        const int pr = QPW * w + q;
        unsigned long long* pl = pool + (size_t)pr * PCAP;
        const int cntw = __builtin_amdgcn_readfirstlane(cnt[pr]);
        const int cnt_ = (cntw < PCAP) ? cntw : PCAP;    // >= 20 guaranteed

        unsigned long long kk = 0ull;
        if (lane < cnt_) kk = pl[lane];

        if (cnt_ <= 64) {
            const unsigned key = (unsigned)(kk >> 32);
            unsigned v = key;
            #pragma unroll
            for (int k = 2; k <= 64; k <<= 1) {
                #pragma unroll
                for (int j = k >> 1; j > 0; j >>= 1) {
                    const unsigned o = (unsigned)__shfl_xor((int)v, j, 64);
                    const bool keep_min = ((lane & j) == 0) == ((lane & k) != 0);
                    v = keep_min ? min(v, o) : max(v, o);
                }
            }
            const unsigned K20 = (unsigned)__shfl((int)v, 19, 64);
            const unsigned long long ge = __ballot(key >= K20);  // pads never match
            if (__popcll(ge) == KNN) {
                if (key >= K20) idxs[pr][mbcnt64(ge)] = (unsigned)kk;
            } else {
                // rare tie path: full u64 sort (value desc, index asc)
                unsigned long long key64 = kk;
                #pragma unroll
                for (int k = 2; k <= 64; k <<= 1) {
                    #pragma unroll
                    for (int j = k >> 1; j > 0; j >>= 1) {
                        const unsigned long long o = __shfl_xor(key64, j, 64);
                        const bool keep_min = ((lane & j) == 0) == ((lane & k) != 0);
                        const unsigned long long mn = (key64 < o) ? key64 : o;
                        const unsigned long long mx = (key64 < o) ? o : key64;
                        key64 = keep_min ? mn : mx;
                    }
                }
                if (lane < KNN) idxs[pr][lane] = (unsigned)key64;
            }
        } else {
            // overflow path: 20 extraction rounds; winners to idxs (disjoint).
            for (int r = 0; r < KNN; ++r) {
                unsigned long long bk = 0ull; int bp = -1;
                for (int i = lane; i < cnt_; i += 64) {
                    const unsigned long long e = pl[i];
                    if (e > bk) { bk = e; bp = i; }
                }
                unsigned long long rb = bk;
                #pragma unroll
                for (int s = 32; s > 0; s >>= 1) {
                    const unsigned long long o = __shfl_xor(rb, s, 64);
                    if (o > rb) rb = o;
                }
                if (bk == rb && bp >= 0) pl[bp] = 0ull;   // unique keys
                if (lane == 0) idxs[pr][r] = (unsigned)rb;
            }
        }
    }

    const unsigned myidxa = idxs[QPW * w][(lane < KNN) ? lane : 0];
    const unsigned myidxb = idxs[QPW * w + 1][(lane < KNN) ? lane : 0];

    // ---- epilogue: lane = output channel; channel constants once per wave ----
    const int o = lane;
    const float iv   = gamma[o] / sqrtf(var[o] + 1e-5f);
    const float bias = beta[o] - mean[o] * iv;
    const float* Wr = Wm + o * 6;
    const float w0p = Wr[0] * iv, w1p = Wr[1] * iv, w2p = Wr[2] * iv;
    const float w3p = Wr[3] * iv, w4p = Wr[4] * iv, w5p = Wr[5] * iv;
    // y = w0p*f0 + w1p*f1 + w2p*f2 + base2   (diff terms folded)
    const float basea = fmaf(w3p, pva.x, fmaf(w4p, pva.y, fmaf(w5p, pva.z, bias)));
    const float base2a = basea - fmaf(w0p, pva.x, fmaf(w1p, pva.y, w2p * pva.z));
    const float baseb = fmaf(w3p, pvb.x, fmaf(w4p, pvb.y, fmaf(w5p, pvb.z, bias)));
    const float base2b = baseb - fmaf(w0p, pvb.x, fmaf(w1p, pvb.y, w2p * pvb.z));

    float besta = -INFINITY, bestb = -INFINITY;
    #pragma unroll
    for (int k = 0; k < KNN; ++k) {
        const int lka = __builtin_amdgcn_readlane((int)myidxa, k);
        const int lkb = __builtin_amdgcn_readlane((int)myidxb, k);
        const int gia = __builtin_amdgcn_readfirstlane((NPTS - 1) - lka);
        const int gib = __builtin_amdgcn_readfirstlane((NPTS - 1) - lkb);
        const float4 fa = xqb[gia];                      // s_load_dwordx4
        const float4 fb = xqb[gib];
        float ya = fmaf(w0p, fa.x, fmaf(w1p, fa.y, fmaf(w2p, fa.z, base2a)));
        float yb = fmaf(w0p, fb.x, fmaf(w1p, fb.y, fmaf(w2p, fb.z, base2b)));
        ya = fmaxf(ya, 0.2f * ya);                       // LeakyReLU
        yb = fmaxf(yb, 0.2f * yb);
        besta = fmaxf(besta, ya);
        bestb = fmaxf(bestb, yb);
    }

    outT[o * (QBLK + 1) + QPW * w]     = besta;
    outT[o * (QBLK + 1) + QPW * w + 1] = bestb;
    __syncthreads();

    // ---- output: 4 x float4 per channel row ----
    if (t < NOUT * 4) {
        const int oo = t >> 2, seg = t & 3;
        const int sb = oo * (QBLK + 1) + seg * 4;
        float4 vv;
        vv.x = outT[sb + 0]; vv.y = outT[sb + 1];
        vv.z = outT[sb + 2]; vv.w = outT[sb + 3];
        *(float4*)(out + ((size_t)b * NOUT + oo) * NPTS + n0 + seg * 4) = vv;
    }
}

extern "C" void kernel_launch(void* const* d_in, const int* in_sizes, int n_in,
                              void* d_out, int out_size, void* d_ws, size_t ws_size,
                              hipStream_t stream) {
    const float* x     = (const float*)d_in[0];
    const float* Wm    = (const float*)d_in[1];
    const float* gamma = (const float*)d_in[2];
    const float* beta  = (const float*)d_in[3];
    const float* mean  = (const float*)d_in[4];
    const float* var   = (const float*)d_in[5];
    float* out = (float*)d_out;
    float4* xq = (float4*)d_ws;                    // B*NPTS float4 = 512 KB

    const int B = in_sizes[0] / (3 * NPTS);        // 8
    pack_kernel<<<B * NPTS / 256, 256, 0, stream>>>(x, xq);
    const int nblocks = B * (NPTS / QBLK);         // 8 * 256 = 2048
    edgeconv_kernel<<<nblocks, BLKT, 0, stream>>>(xq, Wm, gamma, beta, mean, var, out);
}

// Round 11
// 130.558 us; speedup vs baseline: 1.1769x; 1.1042x over previous
//
#include <hip/hip_runtime.h>
#include <math.h>

#define NPTS 4096
#define KNN  20
#define NOUT 64
#define WPB  8               // waves per block
#define QPW  2               // queries per wave
#define QBLK (WPB * QPW)     // 16 queries per block
#define BLKT (WPB * 64)      // 512 threads
#define PCAP 96              // per-query survivor pool capacity (mean ~43, +8 sigma)
#define HALF 2048            // candidates staged in LDS

// monotone float->uint map (total order preserved)
__device__ __forceinline__ unsigned ord32(float f) {
    unsigned u = __float_as_uint(f);
    int m = ((int)u) >> 31;
    return u ^ ((unsigned)m | 0x80000000u);
}
// inverse of ord32
__device__ __forceinline__ float iord32(unsigned r) {
    unsigned u = (r & 0x80000000u) ? (r ^ 0x80000000u) : ~r;
    return __uint_as_float(u);
}
__device__ __forceinline__ int mbcnt64(unsigned long long m) {
    return __builtin_amdgcn_mbcnt_hi((unsigned)(m >> 32),
           __builtin_amdgcn_mbcnt_lo((unsigned)m, 0));
}

// prologue: xq[b][j] = (x0, x1, x2, -(x0^2+x1^2+x2^2))
__global__ __launch_bounds__(256) void pack_kernel(const float* __restrict__ x,
                                                   float4* __restrict__ xq) {
    const int i = blockIdx.x * 256 + threadIdx.x;   // over B*NPTS
    const int b = i >> 12, j = i & (NPTS - 1);
    const float* xb = x + (size_t)b * 3 * NPTS;
    const float a0 = xb[j], a1 = xb[NPTS + j], a2 = xb[2 * NPTS + j];
    xq[i] = make_float4(a0, a1, a2, -fmaf(a0, a0, fmaf(a1, a1, a2 * a2)));
}

__global__ __launch_bounds__(BLKT, 6) void edgeconv_kernel(
    const float4* __restrict__ xq,    // (B, N) packed points
    const float* __restrict__ Wm,     // (64, 6)
    const float* __restrict__ gamma,
    const float* __restrict__ beta,
    const float* __restrict__ mean,
    const float* __restrict__ var,
    float* __restrict__ out)          // (B, 64, N)
{
    const int bid = blockIdx.x;
    const int b   = bid >> 8;                    // 256 blocks per batch
    const int n0  = (bid & 255) * QBLK;
    const int t    = threadIdx.x;
    const int lane = t & 63;
    const int w    = t >> 6;

    __shared__ float4 tile[HALF];                       // 32 KB
    __shared__ unsigned long long pool[QBLK * PCAP];    // 12 KB; idxs/outT alias it
    __shared__ int cnt[QBLK];

    const float4* xqb = xq + (size_t)b * NPTS;

    if (lane < QPW) cnt[QPW * w + lane] = 0;

    // ---- query points (uniform -> scalar loads) ----
    const int na = __builtin_amdgcn_readfirstlane(n0 + QPW * w);
    const float4 pva = xqb[na];
    const float4 pvb = xqb[na + 1];
    const float qa0 = 2.f * pva.x, qa1 = 2.f * pva.y, qa2 = 2.f * pva.z;
    const float qb0 = 2.f * pvb.x, qb1 = 2.f * pvb.y, qb2 = 2.f * pvb.z;

    float vma = -INFINITY, vmb = -INFINITY;

    // ---- stage LDS half; fold staged candidates into lane maxima ----
    #pragma unroll
    for (int k2 = 0; k2 < HALF / BLKT; ++k2) {          // 4 iters
        const int c = t + k2 * BLKT;
        const float4 cc = xqb[c];
        tile[c] = cc;
        const float ea = fmaf(qa0, cc.x, fmaf(qa1, cc.y, fmaf(qa2, cc.z, cc.w)));
        const float eb = fmaf(qb0, cc.x, fmaf(qb1, cc.y, fmaf(qb2, cc.z, cc.w)));
        vma = fmaxf(vma, ea);
        vmb = fmaxf(vmb, eb);
    }

    // ---- G1: stream global half, lane maxima only (VMEM pipe) ----
    #pragma unroll
    for (int g = 4; g < 8; ++g) {
        float4 cc[8];
        #pragma unroll
        for (int u = 0; u < 8; ++u) cc[u] = xqb[(g * 8 + u) * 64 + lane];
        #pragma unroll
        for (int u = 0; u < 8; ++u) {
            const float ea = fmaf(qa0, cc[u].x, fmaf(qa1, cc[u].y, fmaf(qa2, cc[u].z, cc[u].w)));
            const float eb = fmaf(qb0, cc[u].x, fmaf(qb1, cc[u].y, fmaf(qb2, cc[u].z, cc[u].w)));
            vma = fmaxf(vma, ea);
            vmb = fmaxf(vmb, eb);
        }
    }

    // ---- T = 20th largest of 64 lane maxima, via ballot binary search ----
    // (20 distinct candidates >= T  =>  true 20th-best >= T  => superset safe)
    unsigned Ka = 0, Kb = 0;
    {
        const unsigned ka = ord32(vma), kb = ord32(vmb);
        #pragma unroll
        for (int bit = 31; bit >= 0; --bit) {
            const unsigned pa = Ka | (1u << bit);
            const unsigned pb = Kb | (1u << bit);
            const int ca = __popcll(__ballot(ka >= pa));
            const int cb = __popcll(__ballot(kb >= pb));
            if (ca >= KNN) Ka = pa;
            if (cb >= KNN) Kb = pb;
        }
    }
    const float Tfa = iord32(Ka);
    const float Tfb = iord32(Kb);

    __syncthreads();   // tile staged; cnt[] initialized

    const int invl = (NPTS - 1) - lane;
    int* cnta = &cnt[QPW * w];
    int* cntb = &cnt[QPW * w + 1];
    unsigned long long* poola = pool + (size_t)(QPW * w) * PCAP;
    unsigned long long* poolb = pool + (size_t)(QPW * w + 1) * PCAP;

    // ---- pass L: LDS half, single pass, fused filter+append ----
    #pragma unroll
    for (int g = 0; g < 4; ++g) {
        float4 cc[8];
        #pragma unroll
        for (int u = 0; u < 8; ++u) cc[u] = tile[(g * 8 + u) * 64 + lane];
        #pragma unroll
        for (int u = 0; u < 8; ++u) {
            const float ea = fmaf(qa0, cc[u].x, fmaf(qa1, cc[u].y, fmaf(qa2, cc[u].z, cc[u].w)));
            const float eb = fmaf(qb0, cc[u].x, fmaf(qb1, cc[u].y, fmaf(qb2, cc[u].z, cc[u].w)));
            const unsigned tag = (unsigned)(invl - (g * 8 + u) * 64);
            if (ea >= Tfa) {
                const int pos = atomicAdd(cnta, 1);
                if (pos < PCAP)
                    poola[pos] = ((unsigned long long)ord32(ea) << 32) | tag;
            }
            if (eb >= Tfb) {
                const int pos = atomicAdd(cntb, 1);
                if (pos < PCAP)
                    poolb[pos] = ((unsigned long long)ord32(eb) << 32) | tag;
            }
        }
    }

    // ---- G2: global half again, fused filter+append ----
    #pragma unroll
    for (int g = 4; g < 8; ++g) {
        float4 cc[8];
        #pragma unroll
        for (int u = 0; u < 8; ++u) cc[u] = xqb[(g * 8 + u) * 64 + lane];
        #pragma unroll
        for (int u = 0; u < 8; ++u) {
            const float ea = fmaf(qa0, cc[u].x, fmaf(qa1, cc[u].y, fmaf(qa2, cc[u].z, cc[u].w)));
            const float eb = fmaf(qb0, cc[u].x, fmaf(qb1, cc[u].y, fmaf(qb2, cc[u].z, cc[u].w)));
            const unsigned tag = (unsigned)(invl - (g * 8 + u) * 64);
            if (ea >= Tfa) {
                const int pos = atomicAdd(cnta, 1);
                if (pos < PCAP)
                    poola[pos] = ((unsigned long long)ord32(ea) << 32) | tag;
            }
            if (eb >= Tfb) {
                const int pos = atomicAdd(cntb, 1);
                if (pos < PCAP)
                    poolb[pos] = ((unsigned long long)ord32(eb) << 32) | tag;
            }
        }
    }

    // ---- exact top-20 set per query: ballot bsearch, 2 entries/lane ----
    unsigned myidx[QPW];
    #pragma unroll
    for (int q = 0; q < QPW; ++q) {
        const int pr = QPW * w + q;
        unsigned long long* pl = pool + (size_t)pr * PCAP;
        int cw = __builtin_amdgcn_readfirstlane(cnt[pr]);
        if (cw > PCAP) cw = PCAP;                      // >= 20 guaranteed

        // sentinel 0: ord32(finite) >= 1, so invalid entries never counted
        const unsigned long long e0 = (lane < cw) ? pl[lane] : 0ull;
        const unsigned long long e1 = (lane + 64 < cw) ? pl[lane + 64] : 0ull;
        const unsigned k0 = (unsigned)(e0 >> 32), t0 = (unsigned)e0;
        const unsigned k1 = (unsigned)(e1 >> 32), t1 = (unsigned)e1;

        unsigned K = 0;
        #pragma unroll
        for (int bit = 31; bit >= 0; --bit) {
            const unsigned p = K | (1u << bit);
            const int c = __popcll(__ballot(k0 >= p)) + __popcll(__ballot(k1 >= p));
            if (c >= KNN) K = p;
        }

        unsigned long long g0 = __ballot(k0 > K);
        unsigned long long g1 = __ballot(k1 > K);
        const int m = __popcll(g0) + __popcll(g1);     // always <= 19
        unsigned long long q0 = __ballot(k0 == K);
        unsigned long long q1 = __ballot(k1 == K);
        const int r = KNN - m;                         // >= 1 ties needed
        if (__popcll(q0) + __popcll(q1) > r) {
            // tie split: choose r ties with largest tag (= lowest index)
            unsigned TT = 0;
            #pragma unroll
            for (int bit = 11; bit >= 0; --bit) {      // tags < 4096
                const unsigned p = TT | (1u << bit);
                const int c = __popcll(__ballot(k0 == K && t0 >= p)) +
                              __popcll(__ballot(k1 == K && t1 >= p));
                if (c >= r) TT = p;
            }
            q0 = __ballot(k0 == K && t0 >= TT);
            q1 = __ballot(k1 == K && t1 >= TT);
        }

        unsigned* idxq = (unsigned*)pl;                // alias own (consumed) pool
        if ((g0 >> lane) & 1) idxq[mbcnt64(g0)] = t0;
        if ((g1 >> lane) & 1) idxq[__popcll(g0) + mbcnt64(g1)] = t1;
        if ((q0 >> lane) & 1) idxq[m + mbcnt64(q0)] = t0;
        if ((q1 >> lane) & 1) idxq[m + __popcll(q0) + mbcnt64(q1)] = t1;
        myidx[q] = idxq[(lane < KNN) ? lane : 0];
    }

    __syncthreads();   // all pools consumed -> safe to alias as outT

    // ---- epilogue: lane = output channel; neighbors via scalar loads ----
    const int o = lane;
    const float iv   = gamma[o] / sqrtf(var[o] + 1e-5f);
    const float bias = beta[o] - mean[o] * iv;
    const float* Wr = Wm + o * 6;
    const float w0p = Wr[0] * iv, w1p = Wr[1] * iv, w2p = Wr[2] * iv;
    const float w3p = Wr[3] * iv, w4p = Wr[4] * iv, w5p = Wr[5] * iv;
    const float basea = fmaf(w3p, pva.x, fmaf(w4p, pva.y, fmaf(w5p, pva.z, bias)));
    const float base2a = basea - fmaf(w0p, pva.x, fmaf(w1p, pva.y, w2p * pva.z));
    const float baseb = fmaf(w3p, pvb.x, fmaf(w4p, pvb.y, fmaf(w5p, pvb.z, bias)));
    const float base2b = baseb - fmaf(w0p, pvb.x, fmaf(w1p, pvb.y, w2p * pvb.z));

    float besta = -INFINITY, bestb = -INFINITY;
    #pragma unroll
    for (int k = 0; k < KNN; ++k) {
        const int lka = __builtin_amdgcn_readlane((int)myidx[0], k);
        const int lkb = __builtin_amdgcn_readlane((int)myidx[1], k);
        const int gia = __builtin_amdgcn_readfirstlane((NPTS - 1) - lka);
        const int gib = __builtin_amdgcn_readfirstlane((NPTS - 1) - lkb);
        const float4 fa = xqb[gia];                    // s_load_dwordx4
        const float4 fb = xqb[gib];
        float ya = fmaf(w0p, fa.x, fmaf(w1p, fa.y, fmaf(w2p, fa.z, base2a)));
        float yb = fmaf(w0p, fb.x, fmaf(w1p, fb.y, fmaf(w2p, fb.z, base2b)));
        ya = fmaxf(ya, 0.2f * ya);                     // LeakyReLU
        yb = fmaxf(yb, 0.2f * yb);
        besta = fmaxf(besta, ya);
        bestb = fmaxf(bestb, yb);
    }

    float* outT = (float*)pool;                        // 64 x 17 padded (4.25 KB)
    outT[o * (QBLK + 1) + QPW * w]     = besta;
    outT[o * (QBLK + 1) + QPW * w + 1] = bestb;
    __syncthreads();

    // ---- coalesced output: 4 x float4 per channel row ----
    if (t < NOUT * 4) {
        const int oo = t >> 2, seg = t & 3;
        const int sb = oo * (QBLK + 1) + seg * 4;
        float4 vv;
        vv.x = outT[sb + 0]; vv.y = outT[sb + 1];
        vv.z = outT[sb + 2]; vv.w = outT[sb + 3];
        *(float4*)(out + ((size_t)b * NOUT + oo) * NPTS + n0 + seg * 4) = vv;
    }
}

extern "C" void kernel_launch(void* const* d_in, const int* in_sizes, int n_in,
                              void* d_out, int out_size, void* d_ws, size_t ws_size,
                              hipStream_t stream) {
    const float* x     = (const float*)d_in[0];
    const float* Wm    = (const float*)d_in[1];
    const float* gamma = (const float*)d_in[2];
    const float* beta  = (const float*)d_in[3];
    const float* mean  = (const float*)d_in[4];
    const float* var   = (const float*)d_in[5];
    float* out = (float*)d_out;
    float4* xq = (float4*)d_ws;                    // B*NPTS float4 = 512 KB

    const int B = in_sizes[0] / (3 * NPTS);        // 8
    pack_kernel<<<B * NPTS / 256, 256, 0, stream>>>(x, xq);
    const int nblocks = B * (NPTS / QBLK);         // 8 * 256 = 2048
    edgeconv_kernel<<<nblocks, BLKT, 0, stream>>>(xq, Wm, gamma, beta, mean, var, out);
}